// Round 2
// baseline (7263.895 us; speedup 1.0000x reference)
//
#include <hip/hip_runtime.h>
#include <hip/hip_bf16.h>
#include <cstdint>

#define BB 16
#define DD 384
#define LL 8
#define HH 1536
#define EE 8
#define NHEADS 6
#define HDIM 64
#define NTOK 197
#define NPATCH 196
#define TT (BB*NTOK)       // 3152
#define TK2 (TT*2)         // 6304
#define PADCAP 6560        // >= max padded rows (6552)
#define MOE_ROWTILES 205

__device__ __forceinline__ float gelu_f(float x) {
    return 0.5f * x * (1.0f + erff(x * 0.70710678118654752440f));
}

// ---------------- patchify: [B,3,224,224] -> [B*196, 768] ----------------
__global__ __launch_bounds__(256) void patchify_k(const float* __restrict__ X,
                                                  float* __restrict__ XP) {
    int idx = blockIdx.x * 256 + threadIdx.x;
    if (idx >= NPATCH * BB * 768) return;
    int row = idx / 768, f = idx % 768;
    int c = f >> 8, pi = (f >> 4) & 15, pj = f & 15;
    int b = row / NPATCH, p = row % NPATCH;
    int gi = p / 14, gj = p % 14;
    XP[idx] = X[(((size_t)(b * 3 + c) * 224 + gi * 16 + pi) * 224) + gj * 16 + pj];
}

// ---------------- cls row fill ----------------
__global__ __launch_bounds__(256) void cls_fill_k(const float* __restrict__ cls_tok,
                                                  const float* __restrict__ pos,
                                                  float* __restrict__ T) {
    int i = blockIdx.x * 256 + threadIdx.x;
    if (i >= BB * DD) return;
    int b = i / DD, d = i % DD;
    T[(size_t)b * NTOK * DD + d] = cls_tok[d] + pos[d];
}

// ---------------- generic tiled f32 GEMM ----------------
// MODE 0: Out = A@B + bias
// MODE 1: Out = gelu(A@B + bias)
// MODE 2: Out = Cin + A@B + bias        (residual; Cin may alias Out)
// MODE 3: patch-embed: out row remap + pos_embed add
template<int MODE>
__global__ __launch_bounds__(256) void gemm32(const float* __restrict__ A,
                                              const float* __restrict__ Bm,
                                              const float* __restrict__ bias,
                                              const float* __restrict__ Cin,
                                              float* __restrict__ Out,
                                              int M, int N, int Kd,
                                              const float* __restrict__ pos) {
    __shared__ float As[32][33];
    __shared__ float Bs[32][33];
    const int tid = threadIdx.x;
    const int row0 = blockIdx.x * 32, col0 = blockIdx.y * 32;
    const int lr = tid / 8, lk4 = (tid % 8) * 4;   // load coords
    const int tr = tid / 32, tc = tid % 32;        // compute coords
    float acc[4] = {0.f, 0.f, 0.f, 0.f};

    for (int k0 = 0; k0 < Kd; k0 += 32) {
        // A tile (Kd always multiple of 32; guard rows)
        {
            int gr = row0 + lr;
            float4 v = make_float4(0.f, 0.f, 0.f, 0.f);
            if (gr < M) v = *(const float4*)(A + (size_t)gr * Kd + k0 + lk4);
            As[lr][lk4 + 0] = v.x; As[lr][lk4 + 1] = v.y;
            As[lr][lk4 + 2] = v.z; As[lr][lk4 + 3] = v.w;
        }
        // B tile (guard cols for N=1000)
        {
            int gk = k0 + lr;
            int gc = col0 + lk4;
            const float* bp = Bm + (size_t)gk * N + gc;
            float4 v;
            if (gc + 3 < N) v = *(const float4*)bp;
            else {
                v.x = (gc + 0 < N) ? bp[0] : 0.f;
                v.y = (gc + 1 < N) ? bp[1] : 0.f;
                v.z = (gc + 2 < N) ? bp[2] : 0.f;
                v.w = (gc + 3 < N) ? bp[3] : 0.f;
            }
            Bs[lr][lk4 + 0] = v.x; Bs[lr][lk4 + 1] = v.y;
            Bs[lr][lk4 + 2] = v.z; Bs[lr][lk4 + 3] = v.w;
        }
        __syncthreads();
        #pragma unroll
        for (int kk = 0; kk < 32; kk++) {
            float bv = Bs[kk][tc];
            acc[0] += As[tr +  0][kk] * bv;
            acc[1] += As[tr +  8][kk] * bv;
            acc[2] += As[tr + 16][kk] * bv;
            acc[3] += As[tr + 24][kk] * bv;
        }
        __syncthreads();
    }

    int gc = col0 + tc;
    if (gc >= N) return;
    float bv = bias ? bias[gc] : 0.f;
    #pragma unroll
    for (int i = 0; i < 4; i++) {
        int gr = row0 + tr + 8 * i;
        if (gr >= M) continue;
        float val = acc[i] + bv;
        if (MODE == 1) val = gelu_f(val);
        if (MODE == 2) val += Cin[(size_t)gr * N + gc];
        if (MODE == 3) {
            int p = gr % NPATCH;
            int orow = gr + gr / NPATCH + 1;
            val += pos[(size_t)(p + 1) * DD + gc];
            Out[(size_t)orow * N + gc] = val;
        } else {
            Out[(size_t)gr * N + gc] = val;
        }
    }
}

// ---------------- layernorm (two-pass, matches reference) ----------------
__global__ __launch_bounds__(128) void ln_k(const float* __restrict__ X,
                                            const float* __restrict__ w,
                                            const float* __restrict__ b,
                                            float* __restrict__ Y,
                                            int in_stride, int out_stride) {
    int t = blockIdx.x, tid = threadIdx.x;
    const float* x = X + (size_t)t * in_stride;
    float* y = Y + (size_t)t * out_stride;
    float v0 = x[tid], v1 = x[tid + 128], v2 = x[tid + 256];
    __shared__ float red[128];
    red[tid] = v0 + v1 + v2;
    __syncthreads();
    for (int s = 64; s > 0; s >>= 1) { if (tid < s) red[tid] += red[tid + s]; __syncthreads(); }
    float mu = red[0] * (1.f / 384.f);
    __syncthreads();
    float d0 = v0 - mu, d1 = v1 - mu, d2 = v2 - mu;
    red[tid] = d0 * d0 + d1 * d1 + d2 * d2;
    __syncthreads();
    for (int s = 64; s > 0; s >>= 1) { if (tid < s) red[tid] += red[tid + s]; __syncthreads(); }
    float inv = rsqrtf(red[0] * (1.f / 384.f) + 1e-6f);
    y[tid]       = d0 * inv * w[tid]       + b[tid];
    y[tid + 128] = d1 * inv * w[tid + 128] + b[tid + 128];
    y[tid + 256] = d2 * inv * w[tid + 256] + b[tid + 256];
}

// ---------------- attention: scores + softmax ----------------
__global__ __launch_bounds__(256) void attn_scores_k(const float* __restrict__ QKV,
                                                     float* __restrict__ P) {
    int i = blockIdx.x, h = blockIdx.y, b = blockIdx.z;
    int tid = threadIdx.x;
    __shared__ float qs[HDIM];
    __shared__ float red[256];
    if (tid < HDIM) qs[tid] = QKV[(size_t)(b * NTOK + i) * 1152 + h * HDIM + tid];
    __syncthreads();
    float s = -1e30f;
    if (tid < NTOK) {
        const float* kr = QKV + (size_t)(b * NTOK + tid) * 1152 + DD + h * HDIM;
        float d = 0.f;
        #pragma unroll
        for (int e = 0; e < HDIM; e++) d += qs[e] * kr[e];
        s = d * 0.125f;
    }
    red[tid] = s;
    __syncthreads();
    for (int st = 128; st > 0; st >>= 1) { if (tid < st) red[tid] = fmaxf(red[tid], red[tid + st]); __syncthreads(); }
    float mx = red[0];
    __syncthreads();
    float ex = (tid < NTOK) ? expf(s - mx) : 0.f;
    red[tid] = ex;
    __syncthreads();
    for (int st = 128; st > 0; st >>= 1) { if (tid < st) red[tid] += red[tid + st]; __syncthreads(); }
    float inv = 1.f / red[0];
    if (tid < NTOK) P[(((size_t)(b * NHEADS + h) * NTOK) + i) * NTOK + tid] = ex * inv;
}

// ---------------- attention: P @ V ----------------
__global__ __launch_bounds__(64) void attn_pv_k(const float* __restrict__ QKV,
                                                const float* __restrict__ P,
                                                float* __restrict__ O) {
    int i = blockIdx.x, h = blockIdx.y, b = blockIdx.z;
    int e = threadIdx.x;
    const float* pr = P + (((size_t)(b * NHEADS + h) * NTOK) + i) * NTOK;
    const float* vb = QKV + (size_t)b * NTOK * 1152 + 2 * DD + h * HDIM + e;
    float o = 0.f;
    for (int j = 0; j < NTOK; j++) o += pr[j] * vb[(size_t)j * 1152];
    O[((size_t)(b * NTOK + i)) * DD + h * HDIM + e] = o;
}

// ---------------- MoE ----------------
__global__ __launch_bounds__(256) void moe_init_k(int* cnt, int* cnt2, int* perm, int n) {
    int i = blockIdx.x * 256 + threadIdx.x;
    if (i < 8) { cnt[i] = 0; cnt2[i] = 0; }
    if (i < n) perm[i] = -1;
}

__global__ __launch_bounds__(256) void moe_gate_k(const float* __restrict__ Y,
                                                  const float* __restrict__ GW,
                                                  int* __restrict__ eid,
                                                  float* __restrict__ gts,
                                                  int* __restrict__ cnt) {
    int t = blockIdx.x * 256 + threadIdx.x;
    if (t >= TT) return;
    const float* yr = Y + (size_t)t * DD;
    float lg[EE] = {0.f, 0.f, 0.f, 0.f, 0.f, 0.f, 0.f, 0.f};
    for (int d = 0; d < DD; d++) {
        float yv = yr[d];
        const float* g = GW + (size_t)d * EE;
        #pragma unroll
        for (int e = 0; e < EE; e++) lg[e] += yv * g[e];
    }
    int i0 = 0; float v0 = lg[0];
    #pragma unroll
    for (int e = 1; e < EE; e++) if (lg[e] > v0) { v0 = lg[e]; i0 = e; }
    int i1 = -1; float v1 = -1e30f;
    #pragma unroll
    for (int e = 0; e < EE; e++) if (e != i0 && lg[e] > v1) { v1 = lg[e]; i1 = e; }
    float dexp = expf(v1 - v0);
    float g0 = 1.f / (1.f + dexp), g1 = dexp / (1.f + dexp);
    eid[2 * t] = i0; eid[2 * t + 1] = i1;
    gts[2 * t] = g0; gts[2 * t + 1] = g1;
    atomicAdd(&cnt[i0], 1);
    atomicAdd(&cnt[i1], 1);
}

__global__ void moe_setup_k(const int* __restrict__ cnt, int* __restrict__ segs) {
    segs[0] = 0;
    for (int e = 0; e < EE; e++) segs[e + 1] = segs[e] + ((cnt[e] + 31) & ~31);
}

__global__ __launch_bounds__(256) void moe_scatter_k(const int* __restrict__ eid,
                                                     const float* __restrict__ gts,
                                                     const int* __restrict__ segs,
                                                     int* __restrict__ cnt2,
                                                     int* __restrict__ perm,
                                                     float* __restrict__ wgt) {
    int r = blockIdx.x * 256 + threadIdx.x;
    if (r >= TK2) return;
    int t = r >> 1, e = eid[r];
    int slot = atomicAdd(&cnt2[e], 1);
    int pos = segs[e] + slot;
    perm[pos] = t;
    wgt[pos] = gts[r];
}

// H[pos] = gelu(Y[perm[pos]] @ W1[e] + b1[e])   (N=1536, K=384)
__global__ __launch_bounds__(256) void moe_gemm1_k(const float* __restrict__ Y,
                                                   const int* __restrict__ perm,
                                                   const int* __restrict__ segs,
                                                   const float* __restrict__ W1,
                                                   const float* __restrict__ B1,
                                                   float* __restrict__ H) {
    __shared__ float As[32][33];
    __shared__ float Bs[32][33];
    __shared__ int ssegs[9];
    __shared__ int sperm[32];
    const int tid = threadIdx.x;
    const int row0 = blockIdx.x * 32;
    if (tid < 9) ssegs[tid] = segs[tid];
    if (tid < 32) sperm[tid] = perm[row0 + tid];
    __syncthreads();
    int total = ssegs[8];
    if (row0 >= total) return;
    int e = 0;
    while (e < 7 && ssegs[e + 1] <= row0) e++;
    const float* Bm = W1 + (size_t)e * DD * HH;
    const int col0 = blockIdx.y * 32;
    const int lr = tid / 8, lk4 = (tid % 8) * 4;
    const int tr = tid / 32, tc = tid % 32;
    float acc[4] = {0.f, 0.f, 0.f, 0.f};
    for (int k0 = 0; k0 < DD; k0 += 32) {
        int pr = sperm[lr];
        float4 av = make_float4(0.f, 0.f, 0.f, 0.f);
        if (pr >= 0) av = *(const float4*)(Y + (size_t)pr * DD + k0 + lk4);
        As[lr][lk4 + 0] = av.x; As[lr][lk4 + 1] = av.y;
        As[lr][lk4 + 2] = av.z; As[lr][lk4 + 3] = av.w;
        float4 bv = *(const float4*)(Bm + (size_t)(k0 + lr) * HH + col0 + lk4);
        Bs[lr][lk4 + 0] = bv.x; Bs[lr][lk4 + 1] = bv.y;
        Bs[lr][lk4 + 2] = bv.z; Bs[lr][lk4 + 3] = bv.w;
        __syncthreads();
        #pragma unroll
        for (int kk = 0; kk < 32; kk++) {
            float b = Bs[kk][tc];
            acc[0] += As[tr +  0][kk] * b;
            acc[1] += As[tr +  8][kk] * b;
            acc[2] += As[tr + 16][kk] * b;
            acc[3] += As[tr + 24][kk] * b;
        }
        __syncthreads();
    }
    int gc = col0 + tc;
    float bb = B1[(size_t)e * HH + gc];
    #pragma unroll
    for (int i = 0; i < 4; i++) {
        int r = tr + 8 * i;
        H[(size_t)(row0 + r) * HH + gc] = gelu_f(acc[i] + bb);
    }
}

// t[perm[pos]] += wgt[pos] * (H[pos] @ W2[e] + b2[e])   (N=384, K=1536)
__global__ __launch_bounds__(256) void moe_gemm2_k(const float* __restrict__ Hm,
                                                   const int* __restrict__ perm,
                                                   const float* __restrict__ wgt,
                                                   const int* __restrict__ segs,
                                                   const float* __restrict__ W2,
                                                   const float* __restrict__ B2,
                                                   float* __restrict__ T) {
    __shared__ float As[32][33];
    __shared__ float Bs[32][33];
    __shared__ int ssegs[9];
    __shared__ int sperm[32];
    __shared__ float swgt[32];
    const int tid = threadIdx.x;
    const int row0 = blockIdx.x * 32;
    if (tid < 9) ssegs[tid] = segs[tid];
    if (tid < 32) { sperm[tid] = perm[row0 + tid]; swgt[tid] = wgt[row0 + tid]; }
    __syncthreads();
    int total = ssegs[8];
    if (row0 >= total) return;
    int e = 0;
    while (e < 7 && ssegs[e + 1] <= row0) e++;
    const float* Bm = W2 + (size_t)e * HH * DD;
    const int col0 = blockIdx.y * 32;
    const int lr = tid / 8, lk4 = (tid % 8) * 4;
    const int tr = tid / 32, tc = tid % 32;
    float acc[4] = {0.f, 0.f, 0.f, 0.f};
    for (int k0 = 0; k0 < HH; k0 += 32) {
        float4 av = *(const float4*)(Hm + (size_t)(row0 + lr) * HH + k0 + lk4);
        As[lr][lk4 + 0] = av.x; As[lr][lk4 + 1] = av.y;
        As[lr][lk4 + 2] = av.z; As[lr][lk4 + 3] = av.w;
        float4 bv = *(const float4*)(Bm + (size_t)(k0 + lr) * DD + col0 + lk4);
        Bs[lr][lk4 + 0] = bv.x; Bs[lr][lk4 + 1] = bv.y;
        Bs[lr][lk4 + 2] = bv.z; Bs[lr][lk4 + 3] = bv.w;
        __syncthreads();
        #pragma unroll
        for (int kk = 0; kk < 32; kk++) {
            float b = Bs[kk][tc];
            acc[0] += As[tr +  0][kk] * b;
            acc[1] += As[tr +  8][kk] * b;
            acc[2] += As[tr + 16][kk] * b;
            acc[3] += As[tr + 24][kk] * b;
        }
        __syncthreads();
    }
    int gc = col0 + tc;
    float bb = B2[(size_t)e * DD + gc];
    #pragma unroll
    for (int i = 0; i < 4; i++) {
        int pr = sperm[tr + 8 * i];
        if (pr >= 0)
            atomicAdd(&T[(size_t)pr * DD + gc], swgt[tr + 8 * i] * (acc[i] + bb));
    }
}

// ---------------- host ----------------
extern "C" void kernel_launch(void* const* d_in, const int* in_sizes, int n_in,
                              void* d_out, int out_size, void* d_ws, size_t ws_size,
                              hipStream_t stream) {
    const float* x       = (const float*)d_in[0];
    const float* patch_w = (const float*)d_in[1];
    const float* patch_b = (const float*)d_in[2];
    const float* cls_tok = (const float*)d_in[3];
    const float* pos_emb = (const float*)d_in[4];
    const float* ln1_w   = (const float*)d_in[5];
    const float* ln1_b   = (const float*)d_in[6];
    const float* qkv_w   = (const float*)d_in[7];
    const float* qkv_b   = (const float*)d_in[8];
    const float* proj_w  = (const float*)d_in[9];
    const float* proj_b  = (const float*)d_in[10];
    const float* ln2_w   = (const float*)d_in[11];
    const float* ln2_b   = (const float*)d_in[12];
    const float* fc1_w   = (const float*)d_in[13];
    const float* fc1_b   = (const float*)d_in[14];
    const float* fc2_w   = (const float*)d_in[15];
    const float* fc2_b   = (const float*)d_in[16];
    const float* gate_w  = (const float*)d_in[17];
    const float* moe_w1  = (const float*)d_in[18];
    const float* moe_b1  = (const float*)d_in[19];
    const float* moe_w2  = (const float*)d_in[20];
    const float* moe_b2  = (const float*)d_in[21];
    const float* norm_w  = (const float*)d_in[22];
    const float* norm_b  = (const float*)d_in[23];
    const float* head_w  = (const float*)d_in[24];
    const float* head_b  = (const float*)d_in[25];
    float* out = (float*)d_out;

    float* ws = (float*)d_ws;
    size_t off = 0;
    auto alloc = [&](size_t n) { float* p = ws + off; off += (n + 3) & ~(size_t)3; return p; };
    float* t    = alloc((size_t)TT * DD);
    float* y    = alloc((size_t)TT * DD);
    float* o    = alloc((size_t)TT * DD);
    float* qkv  = alloc((size_t)TT * 3 * DD);
    float* big  = alloc((size_t)PADCAP * HH);   // union: xp / scores / h / hmoe
    int*   eid  = (int*)alloc(TK2);
    float* gts  = alloc(TK2);
    int*   cnt  = (int*)alloc(8);
    int*   cnt2 = (int*)alloc(8);
    int*   segs = (int*)alloc(12);
    int*   perm = (int*)alloc(PADCAP);
    float* wgt  = alloc(PADCAP);

    // ---- patch embed ----
    float* xp = big;
    patchify_k<<<(NPATCH * BB * 768 + 255) / 256, 256, 0, stream>>>(x, xp);
    cls_fill_k<<<(BB * DD + 255) / 256, 256, 0, stream>>>(cls_tok, pos_emb, t);
    gemm32<3><<<dim3(98, 12), 256, 0, stream>>>(xp, patch_w, patch_b, nullptr, t,
                                                NPATCH * BB, DD, 768, pos_emb);

    for (int i = 0; i < LL; i++) {
        // attention
        ln_k<<<TT, 128, 0, stream>>>(t, ln1_w + i * DD, ln1_b + i * DD, y, DD, DD);
        gemm32<0><<<dim3(99, 36), 256, 0, stream>>>(y, qkv_w + (size_t)i * DD * 3 * DD,
                                                    qkv_b + (size_t)i * 3 * DD, nullptr,
                                                    qkv, TT, 3 * DD, DD, nullptr);
        float* p = big;
        attn_scores_k<<<dim3(NTOK, NHEADS, BB), 256, 0, stream>>>(qkv, p);
        attn_pv_k<<<dim3(NTOK, NHEADS, BB), 64, 0, stream>>>(qkv, p, o);
        gemm32<2><<<dim3(99, 12), 256, 0, stream>>>(o, proj_w + (size_t)i * DD * DD,
                                                    proj_b + (size_t)i * DD, t, t,
                                                    TT, DD, DD, nullptr);
        // FFN
        ln_k<<<TT, 128, 0, stream>>>(t, ln2_w + i * DD, ln2_b + i * DD, y, DD, DD);
        int j = i / 2;
        if ((i & 1) == 0) {
            float* h = big;
            gemm32<1><<<dim3(99, 48), 256, 0, stream>>>(y, fc1_w + (size_t)j * DD * HH,
                                                        fc1_b + (size_t)j * HH, nullptr,
                                                        h, TT, HH, DD, nullptr);
            gemm32<2><<<dim3(99, 12), 256, 0, stream>>>(h, fc2_w + (size_t)j * HH * DD,
                                                        fc2_b + (size_t)j * DD, t, t,
                                                        TT, DD, HH, nullptr);
        } else {
            float* hm = big;
            moe_init_k<<<(PADCAP + 255) / 256, 256, 0, stream>>>(cnt, cnt2, perm, PADCAP);
            moe_gate_k<<<(TT + 255) / 256, 256, 0, stream>>>(y, gate_w + (size_t)j * DD * EE,
                                                             eid, gts, cnt);
            moe_setup_k<<<1, 1, 0, stream>>>(cnt, segs);
            moe_scatter_k<<<(TK2 + 255) / 256, 256, 0, stream>>>(eid, gts, segs, cnt2, perm, wgt);
            moe_gemm1_k<<<dim3(MOE_ROWTILES, HH / 32), 256, 0, stream>>>(
                y, perm, segs, moe_w1 + (size_t)j * EE * DD * HH,
                moe_b1 + (size_t)j * EE * HH, hm);
            moe_gemm2_k<<<dim3(MOE_ROWTILES, DD / 32), 256, 0, stream>>>(
                hm, perm, wgt, segs, moe_w2 + (size_t)j * EE * HH * DD,
                moe_b2 + (size_t)j * EE * DD, t);
        }
    }

    // final LN on cls rows only + head
    ln_k<<<BB, 128, 0, stream>>>(t, norm_w, norm_b, y, NTOK * DD, DD);
    gemm32<0><<<dim3(1, 32), 256, 0, stream>>>(y, head_w, head_b, nullptr, out,
                                               BB, 1000, DD, nullptr);
}

// Round 4
// 2684.457 us; speedup vs baseline: 2.7059x; 2.7059x over previous
//
#include <hip/hip_runtime.h>
#include <hip/hip_bf16.h>
#include <cstdint>

#define TT 3152          // 16*197 tokens
#define NPAD 3200        // padded token rows
#define MOE_CAP 6912     // >= worst-case 64-aligned padded moe rows (6808)
#define MOE_TILES 108    // MOE_CAP/64

typedef float f32x4 __attribute__((ext_vector_type(4)));
typedef __bf16 bf16x8 __attribute__((ext_vector_type(8)));
typedef __bf16 bf16x4 __attribute__((ext_vector_type(4)));

__device__ __forceinline__ float gelu_f(float x) {
    return 0.5f * x * (1.0f + erff(x * 0.70710678118654752440f));
}

// ---------------- patchify: [B,3,224,224] -> bf16 [3136][768] ----------------
__global__ __launch_bounds__(256) void patchify_k(const float* __restrict__ X,
                                                  __bf16* __restrict__ XP) {
    int idx = blockIdx.x * 256 + threadIdx.x;
    if (idx >= 3136 * 768) return;
    int row = idx / 768, f = idx % 768;
    int c = f >> 8, pi = (f >> 4) & 15, pj = f & 15;
    int b = row / 196, p = row % 196;
    int gi = p / 14, gj = p % 14;
    XP[idx] = (__bf16)X[(((size_t)(b * 3 + c) * 224 + gi * 16 + pi) * 224) + gj * 16 + pj];
}

// ---------------- cls row fill (f32 t) ----------------
__global__ __launch_bounds__(256) void cls_fill_k(const float* __restrict__ cls_tok,
                                                  const float* __restrict__ pos,
                                                  float* __restrict__ T) {
    int i = blockIdx.x * 256 + threadIdx.x;
    if (i >= 16 * 384) return;
    int b = i / 384, d = i % 384;
    T[(size_t)b * 197 * 384 + d] = cls_tok[d] + pos[d];
}

// ---------------- weight transpose: W [K][N] f32 -> WT [N][K] bf16, z matrices ----------------
__global__ __launch_bounds__(256) void wtrans_k(const float* __restrict__ W,
                                                __bf16* __restrict__ WT, int K, int N) {
    __shared__ float tile[32][33];
    const int tid = threadIdx.x;
    const size_t zo = (size_t)blockIdx.z * K * N;
    const float* src = W + zo;
    __bf16* dst = WT + zo;
    int n0 = blockIdx.x * 32, k0 = blockIdx.y * 32;
    int lr = tid >> 3, lc = (tid & 7) * 4;
    float4 v = *(const float4*)(src + (size_t)(k0 + lr) * N + n0 + lc);
    tile[lr][lc + 0] = v.x; tile[lr][lc + 1] = v.y;
    tile[lr][lc + 2] = v.z; tile[lr][lc + 3] = v.w;
    __syncthreads();
    bf16x4 o;
    o[0] = (__bf16)tile[lc + 0][lr]; o[1] = (__bf16)tile[lc + 1][lr];
    o[2] = (__bf16)tile[lc + 2][lr]; o[3] = (__bf16)tile[lc + 3][lr];
    *(bf16x4*)(dst + (size_t)(n0 + lr) * K + k0 + lc) = o;
}

// ---------------- MFMA GEMM: C[M][N] = A[M][K](bf16) x BT[N][K](bf16) ----------------
// BM=64, BN=128, 4 waves (2x2), wave tile 32x64, frags 2x4 of 16x16x32.
// MODE 0: OutF = acc + bias                          (qkv)
// MODE 1: OutB = bf16(gelu(acc+bias))                (fc1)
// MODE 2: OutF += acc + bias                         (proj/fc2 residual into t)
// MODE 3: patch embed: t[row remap] = acc+bias+pos
// MODE 4: moe1: A gathered via perm; OutB = bf16(gelu(acc + b1[e]))
// MODE 5: moe2: atomicAdd t[perm[r]] += wgt[r]*(acc + b2[e])
template<int MODE>
__global__ __launch_bounds__(256) void mgemm_k(
    const __bf16* __restrict__ A, const __bf16* __restrict__ BT,
    const float* __restrict__ bias, float* __restrict__ OutF,
    __bf16* __restrict__ OutB, int N, int K,
    const float* __restrict__ pos, const int* __restrict__ perm,
    const float* __restrict__ wgt, const int* __restrict__ segs)
{
    __shared__ alignas(16) __bf16 Asm[64 * 32];
    __shared__ alignas(16) __bf16 Bsm[128 * 32];
    const int tid = threadIdx.x;
    const int wave = tid >> 6, lane = tid & 63;
    const int row0 = blockIdx.x * 64;
    const int col0 = blockIdx.y * 128;

    const __bf16* BTe = BT;
    const float* biase = bias;
    if (MODE == 4 || MODE == 5) {
        if (row0 >= segs[8]) return;
        int e = 0;
        #pragma unroll
        for (int q = 1; q < 8; q++) if (segs[q] <= row0) e = q;
        BTe = BT + (size_t)e * N * K;
        biase = bias + (size_t)e * N;
    }

    // staging source pointers (per-lane); LDS dest = wave-uniform base + lane*16
    int arow_t = wave * 16 + (lane >> 2);
    int asrc_row;
    if (MODE == 4) { int pr = perm[row0 + arow_t]; asrc_row = (pr < 0) ? TT : pr; }
    else asrc_row = row0 + arow_t;
    const __bf16* aptr = A + (size_t)asrc_row * K + (lane & 3) * 8;
    const __bf16* bptr0 = BTe + (size_t)(col0 + wave * 32 + (lane >> 2)) * K + (lane & 3) * 8;
    const __bf16* bptr1 = bptr0 + (size_t)16 * K;

    f32x4 acc[2][4];
    #pragma unroll
    for (int m = 0; m < 2; m++)
        #pragma unroll
        for (int n = 0; n < 4; n++) acc[m][n] = (f32x4){0.f, 0.f, 0.f, 0.f};

    const int wr = wave >> 1, wc = wave & 1;
    const int aoff = (wr * 32 + (lane & 15)) * 32 + (lane >> 4) * 8;
    const int boff = (wc * 64 + (lane & 15)) * 32 + (lane >> 4) * 8;

    for (int k0 = 0; k0 < K; k0 += 32) {
        __builtin_amdgcn_global_load_lds(
            (const __attribute__((address_space(1))) void*)(aptr + k0),
            (__attribute__((address_space(3))) void*)(&Asm[wave * 512]), 16, 0, 0);
        __builtin_amdgcn_global_load_lds(
            (const __attribute__((address_space(1))) void*)(bptr0 + k0),
            (__attribute__((address_space(3))) void*)(&Bsm[wave * 1024]), 16, 0, 0);
        __builtin_amdgcn_global_load_lds(
            (const __attribute__((address_space(1))) void*)(bptr1 + k0),
            (__attribute__((address_space(3))) void*)(&Bsm[wave * 1024 + 512]), 16, 0, 0);
        __syncthreads();
        bf16x8 af[2], bfr[4];
        af[0] = *(const bf16x8*)&Asm[aoff];
        af[1] = *(const bf16x8*)&Asm[aoff + 16 * 32];
        #pragma unroll
        for (int n = 0; n < 4; n++) bfr[n] = *(const bf16x8*)&Bsm[boff + n * 16 * 32];
        #pragma unroll
        for (int m = 0; m < 2; m++)
            #pragma unroll
            for (int n = 0; n < 4; n++)
                acc[m][n] = __builtin_amdgcn_mfma_f32_16x16x32_bf16(af[m], bfr[n], acc[m][n], 0, 0, 0);
        __syncthreads();
    }

    // epilogue: C row = wr*32 + m*16 + (lane>>4)*4 + r ; col = wc*64 + n*16 + (lane&15)
    #pragma unroll
    for (int m = 0; m < 2; m++) {
        #pragma unroll
        for (int r = 0; r < 4; r++) {
            int grow = row0 + wr * 32 + m * 16 + (lane >> 4) * 4 + r;
            #pragma unroll
            for (int n = 0; n < 4; n++) {
                int gcol = col0 + wc * 64 + n * 16 + (lane & 15);
                float v = acc[m][n][r] + biase[gcol];
                if (MODE == 0) {
                    OutF[(size_t)grow * N + gcol] = v;
                } else if (MODE == 1 || MODE == 4) {
                    OutB[(size_t)grow * N + gcol] = (__bf16)gelu_f(v);
                } else if (MODE == 2) {
                    OutF[(size_t)grow * N + gcol] += v;
                } else if (MODE == 3) {
                    int p = grow % 196;
                    int orow = grow + grow / 196 + 1;
                    OutF[(size_t)orow * 384 + gcol] = v + pos[(size_t)(p + 1) * 384 + gcol];
                } else { // 5
                    int pr = perm[grow];
                    if (pr >= 0)
                        atomicAdd(&OutF[(size_t)pr * 384 + gcol], wgt[grow] * v);
                }
            }
        }
    }
}

// ---------------- layernorm (two-pass), templated output type ----------------
template<typename OT>
__global__ __launch_bounds__(128) void ln_k(const float* __restrict__ X,
                                            const float* __restrict__ w,
                                            const float* __restrict__ b,
                                            OT* __restrict__ Y, int in_stride) {
    int t = blockIdx.x, tid = threadIdx.x;
    const float* x = X + (size_t)t * in_stride;
    OT* y = Y + (size_t)t * 384;
    float v0 = x[tid], v1 = x[tid + 128], v2 = x[tid + 256];
    __shared__ float red[128];
    red[tid] = v0 + v1 + v2;
    __syncthreads();
    for (int s = 64; s > 0; s >>= 1) { if (tid < s) red[tid] += red[tid + s]; __syncthreads(); }
    float mu = red[0] * (1.f / 384.f);
    __syncthreads();
    float d0 = v0 - mu, d1 = v1 - mu, d2 = v2 - mu;
    red[tid] = d0 * d0 + d1 * d1 + d2 * d2;
    __syncthreads();
    for (int s = 64; s > 0; s >>= 1) { if (tid < s) red[tid] += red[tid + s]; __syncthreads(); }
    float inv = rsqrtf(red[0] * (1.f / 384.f) + 1e-6f);
    y[tid]       = (OT)(d0 * inv * w[tid]       + b[tid]);
    y[tid + 128] = (OT)(d1 * inv * w[tid + 128] + b[tid + 128]);
    y[tid + 256] = (OT)(d2 * inv * w[tid + 256] + b[tid + 256]);
}

// ---------------- fused attention: one block per (q-tile of 32, head, batch) ----------------
__global__ __launch_bounds__(256) void attn_fused_k(const float* __restrict__ QKV,
                                                    __bf16* __restrict__ O) {
    const int qt = blockIdx.x, h = blockIdx.y, b = blockIdx.z;
    const int q0 = qt * 32;
    __shared__ float Qs[32][72];
    __shared__ float Ss[32][200];
    const int tid = threadIdx.x;
    {   // load Q tile (rows clamped; invalid rows discarded at the end)
        int r = tid >> 3, c0 = (tid & 7) * 8;
        int qrow = q0 + r; if (qrow > 196) qrow = 196;
        const float4* src = (const float4*)(QKV + ((size_t)(b * 197 + qrow)) * 1152 + h * 64 + c0);
        *(float4*)&Qs[r][c0] = src[0];
        *(float4*)&Qs[r][c0 + 4] = src[1];
    }
    __syncthreads();
    const int r = tid >> 3, j = tid & 7;
    const bool valid = (q0 + r) < 197;
    const float4* q4 = (const float4*)&Qs[r][0];
    float mx = -1e30f;
    for (int k = j; k < 197; k += 8) {
        const float4* k4 = (const float4*)(QKV + ((size_t)(b * 197 + k)) * 1152 + 384 + h * 64);
        float d = 0.f;
        #pragma unroll
        for (int e = 0; e < 16; e++) {
            float4 qv = q4[e], kv = k4[e];
            d += qv.x * kv.x + qv.y * kv.y + qv.z * kv.z + qv.w * kv.w;
        }
        d *= 0.125f;
        Ss[r][k] = d;
        mx = fmaxf(mx, d);
    }
    mx = fmaxf(mx, __shfl_xor(mx, 1));
    mx = fmaxf(mx, __shfl_xor(mx, 2));
    mx = fmaxf(mx, __shfl_xor(mx, 4));
    float sum = 0.f;
    for (int k = j; k < 197; k += 8) {
        float p = __expf(Ss[r][k] - mx);
        Ss[r][k] = p;
        sum += p;
    }
    sum += __shfl_xor(sum, 1);
    sum += __shfl_xor(sum, 2);
    sum += __shfl_xor(sum, 4);
    float inv = 1.f / sum;
    __syncthreads();
    // PV: thread (r,j) computes dims j*8..j*8+8
    float o[8] = {0.f, 0.f, 0.f, 0.f, 0.f, 0.f, 0.f, 0.f};
    for (int k = 0; k < 197; k++) {
        float p = Ss[r][k];
        const float4* vr = (const float4*)(QKV + ((size_t)(b * 197 + k)) * 1152 + 768 + h * 64 + j * 8);
        float4 a = vr[0], c = vr[1];
        o[0] += p * a.x; o[1] += p * a.y; o[2] += p * a.z; o[3] += p * a.w;
        o[4] += p * c.x; o[5] += p * c.y; o[6] += p * c.z; o[7] += p * c.w;
    }
    if (valid) {
        bf16x8 ov;
        #pragma unroll
        for (int e = 0; e < 8; e++) ov[e] = (__bf16)(o[e] * inv);
        *(bf16x8*)(O + ((size_t)(b * 197 + q0 + r)) * 384 + h * 64 + j * 8) = ov;
    }
}

// ---------------- MoE plumbing ----------------
__global__ __launch_bounds__(256) void moe_init_k(int* cnt, int* cnt2, int* perm) {
    int i = blockIdx.x * 256 + threadIdx.x;
    if (i < 8) { cnt[i] = 0; cnt2[i] = 0; }
    if (i < MOE_CAP) perm[i] = -1;
}

// fused f32 LN + gate top-2 (decisions from f32 to match reference tie-breaking)
__global__ __launch_bounds__(256) void lngate_k(const float* __restrict__ T,
                                                const float* __restrict__ lnw,
                                                const float* __restrict__ lnb,
                                                const float* __restrict__ GW,
                                                int* __restrict__ eid,
                                                float* __restrict__ gts,
                                                int* __restrict__ cnt) {
    int tid = threadIdx.x;
    int lt = tid >> 3, e = tid & 7;
    int tok = blockIdx.x * 32 + lt;
    bool v = tok < TT;
    const float* xr = T + (size_t)(v ? tok : TT - 1) * 384;
    float s = 0.f;
    for (int d = e * 48; d < e * 48 + 48; d++) s += xr[d];
    s += __shfl_xor(s, 1); s += __shfl_xor(s, 2); s += __shfl_xor(s, 4);
    float mu = s * (1.f / 384.f);
    float s2 = 0.f;
    for (int d = e * 48; d < e * 48 + 48; d++) { float dd = xr[d] - mu; s2 += dd * dd; }
    s2 += __shfl_xor(s2, 1); s2 += __shfl_xor(s2, 2); s2 += __shfl_xor(s2, 4);
    float inv = rsqrtf(s2 * (1.f / 384.f) + 1e-6f);
    float lg = 0.f;
    for (int d = 0; d < 384; d++) {
        float yv = (xr[d] - mu) * inv * lnw[d] + lnb[d];
        lg += yv * GW[(size_t)d * 8 + e];
    }
    int lane = tid & 63, base = lane & ~7;
    float l[8];
    #pragma unroll
    for (int k = 0; k < 8; k++) l[k] = __shfl(lg, base + k);
    if (e == 0 && v) {
        int i0 = 0; float v0 = l[0];
        #pragma unroll
        for (int k = 1; k < 8; k++) if (l[k] > v0) { v0 = l[k]; i0 = k; }
        int i1 = -1; float v1 = -1e30f;
        #pragma unroll
        for (int k = 0; k < 8; k++) if (k != i0 && l[k] > v1) { v1 = l[k]; i1 = k; }
        float dexp = expf(v1 - v0);
        float g0 = 1.f / (1.f + dexp);
        eid[2 * tok] = i0; eid[2 * tok + 1] = i1;
        gts[2 * tok] = g0; gts[2 * tok + 1] = dexp * g0;
        atomicAdd(&cnt[i0], 1);
        atomicAdd(&cnt[i1], 1);
    }
}

__global__ void moe_setup_k(const int* __restrict__ cnt, int* __restrict__ segs) {
    segs[0] = 0;
    for (int e = 0; e < 8; e++) segs[e + 1] = segs[e] + ((cnt[e] + 63) & ~63);
}

__global__ __launch_bounds__(256) void moe_scatter_k(const int* __restrict__ eid,
                                                     const float* __restrict__ gts,
                                                     const int* __restrict__ segs,
                                                     int* __restrict__ cnt2,
                                                     int* __restrict__ perm,
                                                     float* __restrict__ wgt) {
    int rr = blockIdx.x * 256 + threadIdx.x;
    if (rr >= 2 * TT) return;
    int t = rr >> 1, e = eid[rr];
    int slot = atomicAdd(&cnt2[e], 1);
    int pos = segs[e] + slot;
    perm[pos] = t;
    wgt[pos] = gts[rr];
}

// ---------------- head: [16][384] f32 @ [384][1000] + bias ----------------
__global__ __launch_bounds__(256) void head_k(const float* __restrict__ Yf,
                                              const float* __restrict__ W,
                                              const float* __restrict__ Bb,
                                              float* __restrict__ Out) {
    int id = blockIdx.x * 256 + threadIdx.x;
    if (id >= 16000) return;
    int m = id / 1000, n = id % 1000;
    const float* yr = Yf + (size_t)m * 384;
    float a = 0.f;
    for (int k = 0; k < 384; k++) a += yr[k] * W[(size_t)k * 1000 + n];
    Out[id] = a + Bb[n];
}

// ---------------- host ----------------
extern "C" void kernel_launch(void* const* d_in, const int* in_sizes, int n_in,
                              void* d_out, int out_size, void* d_ws, size_t ws_size,
                              hipStream_t stream) {
    const float* x       = (const float*)d_in[0];
    const float* patch_w = (const float*)d_in[1];
    const float* patch_b = (const float*)d_in[2];
    const float* cls_tok = (const float*)d_in[3];
    const float* pos_emb = (const float*)d_in[4];
    const float* ln1_w   = (const float*)d_in[5];
    const float* ln1_b   = (const float*)d_in[6];
    const float* qkv_w   = (const float*)d_in[7];
    const float* qkv_b   = (const float*)d_in[8];
    const float* proj_w  = (const float*)d_in[9];
    const float* proj_b  = (const float*)d_in[10];
    const float* ln2_w   = (const float*)d_in[11];
    const float* ln2_b   = (const float*)d_in[12];
    const float* fc1_w   = (const float*)d_in[13];
    const float* fc1_b   = (const float*)d_in[14];
    const float* fc2_w   = (const float*)d_in[15];
    const float* fc2_b   = (const float*)d_in[16];
    const float* gate_w  = (const float*)d_in[17];
    const float* moe_w1  = (const float*)d_in[18];
    const float* moe_b1  = (const float*)d_in[19];
    const float* moe_w2  = (const float*)d_in[20];
    const float* moe_b2  = (const float*)d_in[21];
    const float* norm_w  = (const float*)d_in[22];
    const float* norm_b  = (const float*)d_in[23];
    const float* head_w  = (const float*)d_in[24];
    const float* head_b  = (const float*)d_in[25];
    float* out = (float*)d_out;

    char* wsb = (char*)d_ws;
    size_t off = 0;
    auto alloc = [&](size_t bytes) -> void* {
        void* p = wsb + off; off = (off + bytes + 255) & ~(size_t)255; return p;
    };
    float*  t       = (float*) alloc((size_t)NPAD * 384 * 4);
    __bf16* yb      = (__bf16*)alloc((size_t)NPAD * 384 * 2);
    float*  yf      = (float*) alloc((size_t)16 * 384 * 4);
    float*  qkv     = (float*) alloc((size_t)NPAD * 1152 * 4);
    __bf16* ob      = (__bf16*)alloc((size_t)NPAD * 384 * 2);
    __bf16* hb      = (__bf16*)alloc((size_t)MOE_CAP * 1536 * 2);
    __bf16* xpb     = (__bf16*)alloc((size_t)3136 * 768 * 2);
    __bf16* wpatchT = (__bf16*)alloc((size_t)384 * 768 * 2);
    __bf16* wqkvT   = (__bf16*)alloc((size_t)8 * 1152 * 384 * 2);
    __bf16* wprojT  = (__bf16*)alloc((size_t)8 * 384 * 384 * 2);
    __bf16* wfc1T   = (__bf16*)alloc((size_t)4 * 1536 * 384 * 2);
    __bf16* wfc2T   = (__bf16*)alloc((size_t)4 * 384 * 1536 * 2);
    __bf16* w1t     = (__bf16*)alloc((size_t)8 * 1536 * 384 * 2);
    __bf16* w2t     = (__bf16*)alloc((size_t)8 * 384 * 1536 * 2);
    int*    eid     = (int*)   alloc((size_t)2 * TT * 4);
    float*  gts     = (float*) alloc((size_t)2 * TT * 4);
    int*    cnt     = (int*)   alloc(32);
    int*    cnt2    = (int*)   alloc(32);
    int*    segs    = (int*)   alloc(64);
    int*    perm    = (int*)   alloc((size_t)MOE_CAP * 4);
    float*  wgt     = (float*) alloc((size_t)MOE_CAP * 4);

    // ---- weight transposes (dense, once per call) ----
    wtrans_k<<<dim3(12, 24, 1), 256, 0, stream>>>(patch_w, wpatchT, 768, 384);
    wtrans_k<<<dim3(36, 12, 8), 256, 0, stream>>>(qkv_w,  wqkvT,  384, 1152);
    wtrans_k<<<dim3(12, 12, 8), 256, 0, stream>>>(proj_w, wprojT, 384, 384);
    wtrans_k<<<dim3(48, 12, 4), 256, 0, stream>>>(fc1_w,  wfc1T,  384, 1536);
    wtrans_k<<<dim3(12, 48, 4), 256, 0, stream>>>(fc2_w,  wfc2T,  1536, 384);

    // ---- patch embed ----
    patchify_k<<<(3136 * 768 + 255) / 256, 256, 0, stream>>>(x, xpb);
    cls_fill_k<<<(16 * 384 + 255) / 256, 256, 0, stream>>>(cls_tok, pos_emb, t);
    mgemm_k<3><<<dim3(49, 3), 256, 0, stream>>>(xpb, wpatchT, patch_b, t, nullptr,
                                                384, 768, pos_emb, nullptr, nullptr, nullptr);

    for (int i = 0; i < 8; i++) {
        int j = i / 2;
        ln_k<__bf16><<<TT, 128, 0, stream>>>(t, ln1_w + i * 384, ln1_b + i * 384, yb, 384);
        mgemm_k<0><<<dim3(50, 9), 256, 0, stream>>>(yb, wqkvT + (size_t)i * 1152 * 384,
                                                    qkv_b + (size_t)i * 1152, qkv, nullptr,
                                                    1152, 384, nullptr, nullptr, nullptr, nullptr);
        attn_fused_k<<<dim3(7, 6, 16), 256, 0, stream>>>(qkv, ob);
        mgemm_k<2><<<dim3(50, 3), 256, 0, stream>>>(ob, wprojT + (size_t)i * 384 * 384,
                                                    proj_b + (size_t)i * 384, t, nullptr,
                                                    384, 384, nullptr, nullptr, nullptr, nullptr);
        ln_k<__bf16><<<TT, 128, 0, stream>>>(t, ln2_w + i * 384, ln2_b + i * 384, yb, 384);
        if ((i & 1) == 0) {
            mgemm_k<1><<<dim3(50, 12), 256, 0, stream>>>(yb, wfc1T + (size_t)j * 1536 * 384,
                                                         fc1_b + (size_t)j * 1536, nullptr, hb,
                                                         1536, 384, nullptr, nullptr, nullptr, nullptr);
            mgemm_k<2><<<dim3(50, 3), 256, 0, stream>>>(hb, wfc2T + (size_t)j * 384 * 1536,
                                                        fc2_b + (size_t)j * 384, t, nullptr,
                                                        384, 1536, nullptr, nullptr, nullptr, nullptr);
        } else {
            moe_init_k<<<(MOE_CAP + 255) / 256, 256, 0, stream>>>(cnt, cnt2, perm);
            lngate_k<<<(TT + 31) / 32, 256, 0, stream>>>(t, ln2_w + i * 384, ln2_b + i * 384,
                                                         gate_w + (size_t)j * 384 * 8, eid, gts, cnt);
            moe_setup_k<<<1, 1, 0, stream>>>(cnt, segs);
            moe_scatter_k<<<(2 * TT + 255) / 256, 256, 0, stream>>>(eid, gts, segs, cnt2, perm, wgt);
            wtrans_k<<<dim3(48, 12, 8), 256, 0, stream>>>(moe_w1 + (size_t)j * 8 * 384 * 1536, w1t, 384, 1536);
            wtrans_k<<<dim3(12, 48, 8), 256, 0, stream>>>(moe_w2 + (size_t)j * 8 * 1536 * 384, w2t, 1536, 384);
            mgemm_k<4><<<dim3(MOE_TILES, 12), 256, 0, stream>>>(yb, w1t, moe_b1 + (size_t)j * 8 * 1536,
                                                                nullptr, hb, 1536, 384,
                                                                nullptr, perm, nullptr, segs);
            mgemm_k<5><<<dim3(MOE_TILES, 3), 256, 0, stream>>>(hb, w2t, moe_b2 + (size_t)j * 8 * 384,
                                                               t, nullptr, 384, 1536,
                                                               nullptr, perm, wgt, segs);
        }
    }

    // final LN on cls rows only + head
    ln_k<float><<<16, 128, 0, stream>>>(t, norm_w, norm_b, yf, 197 * 384);
    head_k<<<(16000 + 255) / 256, 256, 0, stream>>>(yf, head_w, head_b, out);
}